// Round 1
// baseline (864.515 us; speedup 1.0000x reference)
//
#include <hip/hip_runtime.h>
#include <math.h>

// Problem shape (fixed by reference setup_inputs):
//   predictions, ground_truths: [BS=16, SEQ=4096, SRC=4, DIM=257] float32
//   out = sum over (b,src) of sqrt( sum over (seq,dim) diff^2 )
#define BS   16
#define SEQ  4096
#define SRC  4
#define DIM  257
#define ROW4 257                    // float4 per (b,s) row: SRC*DIM/4 = 1028/4
#define NBUCKET (BS * SRC)          // 64
#define CHUNKS 128                  // seq chunks per batch
#define RPB (SEQ / CHUNKS)          // 32 rows per block
#define NBLOCKS (BS * CHUNKS)       // 2048 (== 8 blocks/CU, fully resident)

// src index of element offset e within a 1028-float row [src][dim]
__device__ __forceinline__ int src_of(int e) {
    return (e >= DIM) + (e >= 2 * DIM) + (e >= 3 * DIM);
}

// One block = one (b, 32-row seq chunk), reading a fully CONTIGUOUS slab:
// 32 rows x 4112 B from each tensor. Thread t always covers float4 #t of
// every row (row = exactly 257 aligned float4); its component->src mapping
// is a per-thread constant (only t in {64,128,192} straddle a boundary),
// handled with 3 weighted FMAs into a "hi" accumulator. Tail float4
// (elements 1024..1027, all src 3) done in a tiny strided loop.
// Finalize (sqrt + global sum) is fused via a last-block-done counter.
__global__ __launch_bounds__(256) void fused_dist_kernel(
    const float* __restrict__ pred,
    const float* __restrict__ gt,
    float* __restrict__ ws,
    float* __restrict__ out)
{
    const int b     = blockIdx.x;           // 0..15
    const int chunk = blockIdx.y;           // 0..CHUNKS-1
    const int t     = threadIdx.x;          // 0..255
    const int lane  = t & 63;
    const int wave  = t >> 6;

    // per-thread constant component->src mapping for float4 #t of a row
    const int   e0  = t << 2;
    const int   sLo = src_of(e0);           // src of component 0
    const float wh1 = (float)(src_of(e0 + 1) != sLo);
    const float wh2 = (float)(src_of(e0 + 2) != sLo);
    const float wh3 = (float)(src_of(e0 + 3) != sLo);
    const int   sHi = (sLo < 3) ? sLo + 1 : 3;

    const float4* __restrict__ P = (const float4*)pred;
    const float4* __restrict__ G = (const float4*)gt;
    const int row4_base = (b * SEQ + chunk * RPB) * ROW4;

    float accAll = 0.0f;   // sum of all 4 components' d^2
    float accHi  = 0.0f;   // portion belonging to src sHi (0 for 253/256 threads)
    float accT   = 0.0f;   // row-tail (src 3) portion

    #pragma unroll 2
    for (int r = 0; r < RPB; ++r) {
        const int i = row4_base + r * ROW4 + t;
        float4 p = P[i];
        float4 g = G[i];
        float dx = p.x - g.x, dy = p.y - g.y, dz = p.z - g.z, dw = p.w - g.w;
        float d2x = dx * dx, d2y = dy * dy, d2z = dz * dz, d2w = dw * dw;
        accAll += (d2x + d2y) + (d2z + d2w);
        accHi = fmaf(d2y, wh1, accHi);
        accHi = fmaf(d2z, wh2, accHi);
        accHi = fmaf(d2w, wh3, accHi);
    }

    // tail float4 of each row: elements 1024..1027, all src==3, 16B aligned
    for (int r = t; r < RPB; r += 256) {
        const int i = row4_base + r * ROW4 + 256;
        float4 p = P[i];
        float4 g = G[i];
        float dx = p.x - g.x, dy = p.y - g.y, dz = p.z - g.z, dw = p.w - g.w;
        accT += (dx * dx + dy * dy) + (dz * dz + dw * dw);
    }

    // scatter the two per-thread accumulators into 4 per-src values
    const float accLo = accAll - accHi;
    float a0 = (sLo == 0 ? accLo : 0.0f) + (sHi == 0 ? accHi : 0.0f);
    float a1 = (sLo == 1 ? accLo : 0.0f) + (sHi == 1 ? accHi : 0.0f);
    float a2 = (sLo == 2 ? accLo : 0.0f) + (sHi == 2 ? accHi : 0.0f);
    float a3 = (sLo == 3 ? accLo : 0.0f) + (sHi == 3 ? accHi : 0.0f) + accT;

    // wave64 shuffle reduction of the 4 per-src partials
    #pragma unroll
    for (int o = 32; o > 0; o >>= 1) {
        a0 += __shfl_down(a0, o, 64);
        a1 += __shfl_down(a1, o, 64);
        a2 += __shfl_down(a2, o, 64);
        a3 += __shfl_down(a3, o, 64);
    }

    __shared__ float sred[4][4];
    __shared__ int isLast;
    if (lane == 0) {
        sred[wave][0] = a0; sred[wave][1] = a1;
        sred[wave][2] = a2; sred[wave][3] = a3;
    }
    __syncthreads();
    if (t < 4) {
        atomicAdd(&ws[b * SRC + t],
                  sred[0][t] + sred[1][t] + sred[2][t] + sred[3][t]);
    }
    // release: make this block's bucket adds device-visible before the
    // completion-counter bump (fence-per-thread + barrier, then bump)
    __threadfence();
    __syncthreads();
    if (t == 0) {
        unsigned prev = atomicAdd((unsigned*)(ws + NBUCKET), 1u);
        isLast = (prev == (unsigned)(NBLOCKS - 1));
    }
    __syncthreads();
    if (isLast && wave == 0) {
        // atomic read-modify-write with 0 => coherent read across XCDs
        float v = sqrtf(atomicAdd(&ws[lane], 0.0f));
        #pragma unroll
        for (int o = 32; o > 0; o >>= 1) v += __shfl_down(v, o, 64);
        if (lane == 0) out[0] = v;
    }
}

extern "C" void kernel_launch(void* const* d_in, const int* in_sizes, int n_in,
                              void* d_out, int out_size, void* d_ws, size_t ws_size,
                              hipStream_t stream)
{
    const float* pred = (const float*)d_in[0];
    const float* gt   = (const float*)d_in[1];
    float* ws  = (float*)d_ws;
    float* out = (float*)d_out;

    // d_ws is re-poisoned (0xAA) before every timed launch — zero the 64
    // bucket accumulators + 1 completion counter on-stream.
    hipMemsetAsync(ws, 0, (NBUCKET + 1) * sizeof(float), stream);

    fused_dist_kernel<<<dim3(BS, CHUNKS), 256, 0, stream>>>(pred, gt, ws, out);
}

// Round 2
// 515.420 us; speedup vs baseline: 1.6773x; 1.6773x over previous
//
#include <hip/hip_runtime.h>
#include <math.h>

// Problem shape (fixed by reference setup_inputs):
//   predictions, ground_truths: [BS=16, SEQ=4096, SRC=4, DIM=257] float32
//   out = sum over (b,src) of sqrt( sum over (seq,dim) diff^2 )
#define BS   16
#define SEQ  4096
#define SRC  4
#define DIM  257
#define NBUCKET (BS * SRC)          // 64
#define CHUNKS 32                   // blocks per bucket along seq
#define RPB (SEQ / CHUNKS)          // 128 rows (seq positions) per block
#define RPW (RPB / 4)               // 32 contiguous rows per wave
#define RSTRIDE (SRC * DIM)         // 1028 floats between consecutive seq rows

// Round-0 proven structure (164 us): one block per (bucket, seq-chunk),
// bucket = b*4+src block-uniform, one atomicAdd per block into ws[bucket].
// THIS ROUND'S ONE CHANGE: each wave owns a CONTIGUOUS 32-row run and the
// row loop is manually unrolled x4 with all 8 float4 loads issued before
// any consumption -> 4x per-wave memory-level parallelism (round 0 had
// VGPR_Count=16, i.e. one load-pair in flight, one latency round-trip per
// row => 1.84 TB/s latency-bound).
//
// Row base element offset = ((b*SEQ + s)*SRC + src)*DIM. DIM=257 == 1 (mod 4)
// so base mod 4 == src for every row of a bucket: peel k0=(4-src)&3 scalars,
// bulk is 16B-aligned float4, plus 1- or 2-element row tail.
__global__ __launch_bounds__(256) void bucket_sq_sums(
    const float* __restrict__ pred,
    const float* __restrict__ gt,
    float* __restrict__ ws)
{
    const int bucket = blockIdx.x;          // 0..63
    const int b      = bucket >> 2;
    const int src    = bucket & 3;
    const int chunk  = blockIdx.y;          // 0..CHUNKS-1
    const int wave   = threadIdx.x >> 6;    // 0..3
    const int lane   = threadIdx.x & 63;

    const int k0    = (4 - src) & 3;        // prologue scalars to reach 16B align
    const int n4    = (DIM - k0) >> 2;      // 63 or 64 float4 per row
    const int nscal = DIM - (n4 << 2);      // prologue + tail scalars: 1 or 5

    const int s0 = chunk * RPB + wave * RPW;
    const long long base =
        ((long long)(b * SEQ + s0) * SRC + src) * (long long)DIM + k0;
    const float* __restrict__ p = pred + base;   // 16B-aligned
    const float* __restrict__ g = gt   + base;

    // scalar-element offset for this lane, relative to p (which includes +k0):
    //   lanes [0,k0)        -> prologue elements (negative offsets)
    //   lanes [k0, nscal)   -> row-tail elements after the float4 bulk
    const int  soff = lane - k0 + ((lane < k0) ? 0 : (n4 << 2));
    const bool vact = lane < n4;
    const bool sact = lane < nscal;

    float acc = 0.0f;

    #pragma unroll 1
    for (int j = 0; j < RPW; j += 4) {
        const float* pj = p + j * RSTRIDE;
        const float* gj = g + j * RSTRIDE;

        float4 pv[4], gv[4];
        float  ps[4], gs[4];

        if (vact) {
            #pragma unroll
            for (int u = 0; u < 4; ++u) {
                pv[u] = ((const float4*)(pj + u * RSTRIDE))[lane];
                gv[u] = ((const float4*)(gj + u * RSTRIDE))[lane];
            }
        }
        if (sact) {
            #pragma unroll
            for (int u = 0; u < 4; ++u) {
                ps[u] = pj[u * RSTRIDE + soff];
                gs[u] = gj[u * RSTRIDE + soff];
            }
        }

        if (vact) {
            #pragma unroll
            for (int u = 0; u < 4; ++u) {
                float dx = pv[u].x - gv[u].x;
                float dy = pv[u].y - gv[u].y;
                float dz = pv[u].z - gv[u].z;
                float dw = pv[u].w - gv[u].w;
                acc += (dx * dx + dy * dy) + (dz * dz + dw * dw);
            }
        }
        if (sact) {
            #pragma unroll
            for (int u = 0; u < 4; ++u) {
                float d = ps[u] - gs[u];
                acc += d * d;
            }
        }
    }

    // wave64 shuffle reduction
    #pragma unroll
    for (int o = 32; o > 0; o >>= 1) acc += __shfl_down(acc, o, 64);

    __shared__ float s[4];
    if (lane == 0) s[wave] = acc;
    __syncthreads();
    if (threadIdx.x == 0) {
        atomicAdd(&ws[bucket], s[0] + s[1] + s[2] + s[3]);
    }
}

// Single wave: sqrt each bucket sum, reduce, write scalar output.
__global__ void finalize_kernel(const float* __restrict__ ws,
                                float* __restrict__ out)
{
    const int t = threadIdx.x;              // 0..63 == NBUCKET
    float v = sqrtf(ws[t]);
    #pragma unroll
    for (int o = 32; o > 0; o >>= 1) v += __shfl_down(v, o, 64);
    if (t == 0) out[0] = v;
}

extern "C" void kernel_launch(void* const* d_in, const int* in_sizes, int n_in,
                              void* d_out, int out_size, void* d_ws, size_t ws_size,
                              hipStream_t stream)
{
    const float* pred = (const float*)d_in[0];
    const float* gt   = (const float*)d_in[1];
    float* ws  = (float*)d_ws;
    float* out = (float*)d_out;

    // d_ws is re-poisoned (0xAA) before every timed launch — zero the 64
    // bucket accumulators on-stream (memset nodes are graph-capturable).
    hipMemsetAsync(ws, 0, NBUCKET * sizeof(float), stream);

    bucket_sq_sums<<<dim3(NBUCKET, CHUNKS), 256, 0, stream>>>(pred, gt, ws);
    finalize_kernel<<<1, 64, 0, stream>>>(ws, out);
}